// Round 10
// baseline (892.415 us; speedup 1.0000x reference)
//
#include <hip/hip_runtime.h>
#include <hip/hip_bf16.h>

// AUGRU dynamic RNN: B=1024, T=512, D=128.
// Round-10: 4-WAVE BLOCKS (256 thr), each wave owns TWO column-sets
// (cols 32w+lm and 32w+16+lm; B-frags for both in registers). The A-frag
// b128 LDS reads (ah/axn/arh) are wave-invariant broadcasts -> per-CU read
// count halves (96->48/step). Per-SIMD MFMA/VALU/trans unchanged (1 wave
// doing 2x == 2 waves doing 1x). Kernel is LDS-pipe-bound (R8 exact-2x,
// R9 ledger: reads = 2/3 of pipe time; conflicts proportional to b128
// reads per R3/R9 evidence). Ladder kept: R5 cross-step x-partials, R9
// register-resident h via column-aligned gates, cvt_pk_bf16, folded
// biases, lgkm-only barriers, 2 barriers/step, 64 blocks.

#define Bn 1024
#define Tn 512
#define Dn 128

typedef __attribute__((ext_vector_type(8))) short short8;   // 8 bf16 (4 VGPR)
typedef __attribute__((ext_vector_type(4))) float f32x4;
typedef __attribute__((ext_vector_type(4))) unsigned uint4v;

#define BS 136   // bf16 LDS row stride (shorts): 272 B = 17*16B

#define NL2E  (-1.4426950408889634f)   // -log2(e)
#define N2L2E (-2.8853900817779268f)   // -2*log2(e)

__device__ __forceinline__ short f2bf(float f) {            // cold paths only
    __hip_bfloat16 h = __float2bfloat16(f);   // RNE
    return __builtin_bit_cast(short, h);
}
__device__ __forceinline__ unsigned cvt_pk_bf16(float a, float b) {
    unsigned r;
    asm("v_cvt_pk_bf16_f32 %0, %1, %2" : "=v"(r) : "v"(a), "v"(b));
    return r;
}
// LDS-only barrier: order LDS ops across waves WITHOUT draining vmcnt.
__device__ __forceinline__ void barrier_lds() {
    __builtin_amdgcn_sched_barrier(0);
    asm volatile("s_waitcnt lgkmcnt(0)" ::: "memory");
    __builtin_amdgcn_s_barrier();
    __builtin_amdgcn_sched_barrier(0);
}

#define MFMA_(a, b, c) __builtin_amdgcn_mfma_f32_16x16x32_bf16((a), (b), (c), 0, 0, 0)

__launch_bounds__(256, 1)
__global__ void augru_kernel(const float* __restrict__ X,    // [B,T,D]
                             const float* __restrict__ ATT,  // [B,T,1]
                             const float* __restrict__ GK,   // [256,256]
                             const float* __restrict__ GB,   // [256]
                             const float* __restrict__ CK,   // [256,128]
                             const float* __restrict__ CB,   // [128]
                             const int*   __restrict__ SL,   // [B,1]
                             float* __restrict__ OUT) {      // [B,T,D]
    __shared__ short hb [16 * BS];      // h  (bf16 mirror, A-frag source)
    __shared__ short rhb[16 * BS];      // r*h (bf16, A-frag source)
    __shared__ short xb [2][16 * BS];   // x tile; slot s&1 holds x(s)
    __shared__ float abuf[2][16];
    __shared__ int   lenbuf[16];

    const int tid  = threadIdx.x;
    const int wid  = tid >> 6;          // 0..3
    const int lane = tid & 63;
    const int lm   = lane & 15;
    const int q    = lane >> 4;
    const int b0   = blockIdx.x * 16;

    // wave's two owned cand/r columns; u-cols are +128.
    // s=0: col 32w+lm ; s=1: col 32w+16+lm
    const int colBase = 32 * wid + lm;

    // ---------- preload weight B-frags for both col-sets ----------
    short8 fgx0[2][4], fgx1[2][4], fgh0[2][4], fgh1[2][4], fcx[2][4], fch[2][4];
    float pb0[2], pb1[2], cbp[2];
#pragma unroll
    for (int s = 0; s < 2; ++s) {
        const int c = colBase + 16 * s;
#pragma unroll
        for (int ks = 0; ks < 4; ++ks) {
            short8 v0, v1, v2, v3, v4, v5;
#pragma unroll
            for (int j = 0; j < 8; ++j) {
                const int k = ks * 32 + q * 8 + j;
                v0[j] = f2bf(GK[k * 256 + c]);               // x-part, r col
                v1[j] = f2bf(GK[k * 256 + 128 + c]);         // x-part, u col
                v2[j] = f2bf(GK[(128 + k) * 256 + c]);       // h-part, r col
                v3[j] = f2bf(GK[(128 + k) * 256 + 128 + c]); // h-part, u col
                v4[j] = f2bf(CK[k * 128 + c]);               // cand x-part
                v5[j] = f2bf(CK[(128 + k) * 128 + c]);       // cand rh-part
            }
            fgx0[s][ks] = v0; fgx1[s][ks] = v1;
            fgh0[s][ks] = v2; fgh1[s][ks] = v3;
            fcx[s][ks] = v4;  fch[s][ks] = v5;
        }
        pb0[s] = GB[c]       * NL2E;
        pb1[s] = GB[128 + c] * NL2E;
        cbp[s] = CB[c]       * N2L2E;
    }

    // ---------- init LDS ----------
    for (int i = tid; i < 16 * BS; i += 256) hb[i] = 0;
    if (tid < 16) {
        lenbuf[tid]  = SL[b0 + tid];
        abuf[0][tid] = ATT[(size_t)(b0 + tid) * Tn];
    }
    // x staging: 256 threads, each 8 floats -> one b128 LDS write
    const int prow = tid >> 4;            // 0..15
    const int pc8  = (tid & 15) * 8;      // 8 consecutive floats
#define STAGE_X(slot, tt) {                                                        \
        const float* xp_ = X + ((size_t)(b0 + prow) * Tn + (tt)) * Dn + pc8;       \
        float4 a_ = *(const float4*)xp_;                                           \
        float4 b_ = *(const float4*)(xp_ + 4);                                     \
        uint4v pp_;                                                                \
        pp_[0] = cvt_pk_bf16(a_.x, a_.y); pp_[1] = cvt_pk_bf16(a_.z, a_.w);        \
        pp_[2] = cvt_pk_bf16(b_.x, b_.y); pp_[3] = cvt_pk_bf16(b_.z, b_.w);        \
        *(uint4v*)&xb[slot][prow * BS + pc8] = pp_; }

    STAGE_X(0, 0)
    __syncthreads();

    int len_i[4];
    float h_reg[2][4] = {{0.f,0.f,0.f,0.f},{0.f,0.f,0.f,0.f}};
#pragma unroll
    for (int i = 0; i < 4; ++i) len_i[i] = lenbuf[q * 4 + i];

    // ---------- prologue: x-partials for t=0 (both sets); stage x(1) ----------
    f32x4 gx0A[2], gx1A[2], cxA[2], gx0B[2], gx1B[2], cxB[2];
#pragma unroll
    for (int s = 0; s < 2; ++s) { gx0A[s] = (f32x4){0,0,0,0}; gx1A[s] = (f32x4){0,0,0,0}; cxA[s] = (f32x4){0,0,0,0}; }
    {
        short8 ax0[4];
#pragma unroll
        for (int ks = 0; ks < 4; ++ks)
            ax0[ks] = *(const short8*)&xb[0][lm * BS + ks * 32 + q * 8];
#pragma unroll
        for (int ks = 0; ks < 4; ++ks)
#pragma unroll
            for (int s = 0; s < 2; ++s) {
                gx0A[s] = MFMA_(ax0[ks], fgx0[s][ks], gx0A[s]);
                gx1A[s] = MFMA_(ax0[ks], fgx1[s][ks], gx1A[s]);
                cxA[s]  = MFMA_(ax0[ks], fcx[s][ks],  cxA[s]);
            }
        STAGE_X(1, 1)
    }
    __syncthreads();

#define STEP_BODY(t, GIN0, GIN1, CIN, GOUT0, GOUT1, COUT)                         \
    {                                                                             \
        const int cur = (t) & 1, nxt = cur ^ 1;                                   \
        const int tp1 = ((t) + 1 < Tn) ? (t) + 1 : Tn - 1;                        \
        const int tp2 = ((t) + 2 < Tn) ? (t) + 2 : Tn - 1;                        \
        const float* xp = X + ((size_t)(b0 + prow) * Tn + tp2) * Dn + pc8;        \
        float4 xpre0 = *(const float4*)xp;                                        \
        float4 xpre1 = *(const float4*)(xp + 4);                                  \
        float  apre = (tid < 16) ? ATT[(size_t)(b0 + tid) * Tn + tp1] : 0.0f;     \
        /* A-frags (wave-invariant broadcast reads, once per wave) */             \
        short8 axn[4], ah[4];                                                     \
        _Pragma("unroll")                                                         \
        for (int ks = 0; ks < 4; ++ks) {                                          \
            axn[ks] = *(const short8*)&xb[nxt][lm * BS + ks * 32 + q * 8];        \
            ah[ks]  = *(const short8*)&hb[lm * BS + ks * 32 + q * 8];             \
        }                                                                         \
        /* P1: gates from saved x-partials + h-part; next x-partials float */     \
        f32x4 g0[2], g1[2], n0[2], n1[2], n2[2];                                  \
        _Pragma("unroll")                                                         \
        for (int s = 0; s < 2; ++s) {                                             \
            g0[s] = GIN0[s]; g1[s] = GIN1[s];                                     \
            n0[s] = (f32x4){0,0,0,0}; n1[s] = (f32x4){0,0,0,0}; n2[s] = (f32x4){0,0,0,0}; \
        }                                                                         \
        _Pragma("unroll")                                                         \
        for (int ks = 0; ks < 4; ++ks)                                            \
            _Pragma("unroll")                                                     \
            for (int s = 0; s < 2; ++s) {                                         \
                g0[s] = MFMA_(ah[ks], fgh0[s][ks], g0[s]);                        \
                g1[s] = MFMA_(ah[ks], fgh1[s][ks], g1[s]);                        \
            }                                                                     \
        _Pragma("unroll")                                                         \
        for (int ks = 0; ks < 4; ++ks)                                            \
            _Pragma("unroll")                                                     \
            for (int s = 0; s < 2; ++s) {                                         \
                n0[s] = MFMA_(axn[ks], fgx0[s][ks], n0[s]);                       \
                n1[s] = MFMA_(axn[ks], fgx1[s][ks], n1[s]);                       \
                n2[s] = MFMA_(axn[ks], fcx[s][ks],  n2[s]);                       \
            }                                                                     \
        /* activations (C/D: col s-owned, row q*4+i); all register state */       \
        float am[4], up[2][4];                                                    \
        _Pragma("unroll")                                                         \
        for (int i = 0; i < 4; ++i) am[i] = 1.0f - abuf[cur][q * 4 + i];          \
        _Pragma("unroll")                                                         \
        for (int s = 0; s < 2; ++s) {                                             \
            float rhv[4];                                                         \
            _Pragma("unroll")                                                     \
            for (int i = 0; i < 4; ++i) {                                         \
                const float e0 = __builtin_amdgcn_exp2f(fmaf(g0[s][i], NL2E, pb0[s])); \
                rhv[i] = __builtin_amdgcn_rcpf(1.0f + e0) * h_reg[s][i];          \
                const float e1 = __builtin_amdgcn_exp2f(fmaf(g1[s][i], NL2E, pb1[s])); \
                up[s][i] = am[i] * __builtin_amdgcn_rcpf(1.0f + e1);              \
            }                                                                     \
            const unsigned pA_ = cvt_pk_bf16(rhv[0], rhv[1]);                     \
            const unsigned pB_ = cvt_pk_bf16(rhv[2], rhv[3]);                     \
            const int c_ = colBase + 16 * s;                                      \
            rhb[(q * 4 + 0) * BS + c_] = (short)pA_;                              \
            rhb[(q * 4 + 1) * BS + c_] = (short)(pA_ >> 16);                      \
            rhb[(q * 4 + 2) * BS + c_] = (short)pB_;                              \
            rhb[(q * 4 + 3) * BS + c_] = (short)(pB_ >> 16);                      \
        }                                                                         \
        barrier_lds();                                                            \
        /* P2: cand = saved x-partial + rh-part */                                \
        short8 arh[4];                                                            \
        _Pragma("unroll")                                                         \
        for (int ks = 0; ks < 4; ++ks)                                            \
            arh[ks] = *(const short8*)&rhb[lm * BS + ks * 32 + q * 8];            \
        f32x4 cc[2];                                                              \
        _Pragma("unroll")                                                         \
        for (int s = 0; s < 2; ++s) cc[s] = CIN[s];                               \
        _Pragma("unroll")                                                         \
        for (int ks = 0; ks < 4; ++ks)                                            \
            _Pragma("unroll")                                                     \
            for (int s = 0; s < 2; ++s)                                           \
                cc[s] = MFMA_(arh[ks], fch[s][ks], cc[s]);                        \
        /* h update + output (register state) */                                  \
        _Pragma("unroll")                                                         \
        for (int s = 0; s < 2; ++s) {                                             \
            float hxv[4];                                                         \
            const int c_ = colBase + 16 * s;                                      \
            _Pragma("unroll")                                                     \
            for (int i = 0; i < 4; ++i) {                                         \
                const int row = q * 4 + i;                                        \
                const float e  = __builtin_amdgcn_exp2f(fmaf(cc[s][i], N2L2E, cbp[s])); \
                const float cv = fmaf(2.0f, __builtin_amdgcn_rcpf(1.0f + e), -1.0f); \
                const float hn = fmaf(up[s][i], h_reg[s][i] - cv, cv);            \
                const bool valid = ((t) < len_i[i]);                              \
                const float hnext = valid ? hn : h_reg[s][i];                     \
                OUT[((size_t)(b0 + row) * Tn + (t)) * Dn + c_] = valid ? hn : 0.0f; \
                h_reg[s][i] = hnext;                                              \
                hxv[i] = hnext;                                                   \
            }                                                                     \
            const unsigned pA_ = cvt_pk_bf16(hxv[0], hxv[1]);                     \
            const unsigned pB_ = cvt_pk_bf16(hxv[2], hxv[3]);                     \
            hb[(q * 4 + 0) * BS + c_] = (short)pA_;                               \
            hb[(q * 4 + 1) * BS + c_] = (short)(pA_ >> 16);                       \
            hb[(q * 4 + 2) * BS + c_] = (short)pB_;                               \
            hb[(q * 4 + 3) * BS + c_] = (short)(pB_ >> 16);                       \
        }                                                                         \
        /* stage x(t+2) into xb[cur]; a(t+1) into abuf[nxt] */                    \
        STAGE_X(cur, tp2)                                                         \
        if (tid < 16) abuf[nxt][tid] = apre;                                      \
        (void)xpre0; (void)xpre1;                                                 \
        barrier_lds();                                                            \
        _Pragma("unroll")                                                         \
        for (int s = 0; s < 2; ++s) { GOUT0[s] = n0[s]; GOUT1[s] = n1[s]; COUT[s] = n2[s]; } \
    }

    // ---------- time loop (unrolled x2: static A/B partial sets) ----------
    for (int t = 0; t < Tn; t += 2) {
        STEP_BODY(t,     gx0A, gx1A, cxA, gx0B, gx1B, cxB)
        STEP_BODY(t + 1, gx0B, gx1B, cxB, gx0A, gx1A, cxA)
    }
#undef STEP_BODY
#undef STAGE_X
}

extern "C" void kernel_launch(void* const* d_in, const int* in_sizes, int n_in,
                              void* d_out, int out_size, void* d_ws, size_t ws_size,
                              hipStream_t stream) {
    (void)in_sizes; (void)n_in; (void)d_ws; (void)ws_size; (void)out_size;
    const float* X   = (const float*)d_in[0];
    const float* ATT = (const float*)d_in[1];
    const float* GK  = (const float*)d_in[2];
    const float* GB  = (const float*)d_in[3];
    const float* CK  = (const float*)d_in[4];
    const float* CB  = (const float*)d_in[5];
    const int*   SL  = (const int*)d_in[6];
    float* OUT = (float*)d_out;

    augru_kernel<<<dim3(Bn / 16), dim3(256), 0, stream>>>(X, ATT, GK, GB, CK, CB, SL, OUT);
}